// Round 17
// baseline (125.595 us; speedup 1.0000x reference)
//
#include <hip/hip_runtime.h>
#include <hip/hip_bf16.h>

typedef short bf16x8 __attribute__((ext_vector_type(8)));
typedef float f32x16 __attribute__((ext_vector_type(16)));

#define B_ 2
#define C_ 64
#define L_ 16
#define N_ 32
#define HW_ 4096

// ---- ws byte layout ----
#define BY_WPH  0u          // conv packed weights: 25088 frags * 16B = 401408
#define BY_WP1  401408u     // W_in' B-frags hi/lo
#define BY_WP2  434176u     // W_out B-frags hi/lo
#define BY_OFF1 450560u
#define BY_LR   451072u
#define BY_LI   459264u
#define BY_GM   467456u
#define BY_PART 475648u     // conv per-block gn partials
#define BY_XHI  524288u     // x bf16 plane [n][pix][ic]; after k_pw: u bf16 (in-place)

__device__ __forceinline__ unsigned short f2bf(float v) {
    unsigned int u = __float_as_uint(v);
    unsigned int r = u + 0x7FFFu + ((u >> 16) & 1u);
    return (unsigned short)(r >> 16);
}
__device__ __forceinline__ float bf2f(unsigned short s) {
    return __uint_as_float(((unsigned int)s) << 16);
}

// ---------------- merged: setup (blocks 0..118) | x transpose (blocks 119..1142) ----------------
__global__ __launch_bounds__(256) void k_pre(
    const float* __restrict__ W_sp, const float* __restrict__ W_dc,
    unsigned short* __restrict__ WpH,
    const float* __restrict__ W_in, const float* __restrict__ b_in,
    const float* __restrict__ W_out,
    const float* __restrict__ gn_g, const float* __restrict__ gn_b,
    unsigned short* __restrict__ WP1, unsigned short* __restrict__ WP2,
    float* __restrict__ OFF1,
    const float* __restrict__ dt, const float* __restrict__ nu_log,
    const float* __restrict__ theta_log,
    float* __restrict__ lr_t, float* __restrict__ li_t, float* __restrict__ gm_t,
    const float* __restrict__ x, unsigned short* __restrict__ xhi) {
    __shared__ float t[64][129];
    int blk = blockIdx.x, tid = threadIdx.x;
    if (blk < 98) {
        int idx = blk * 256 + tid;
        int lane = idx & 63;
        int ks   = (idx >> 6) & 3;
        int nf   = (idx >> 8) & 1;
        int tap  = idx >> 9;
        int oc   = nf * 32 + (lane & 31);
        int icb  = ks * 16 + (lane >> 5) * 8;
        unsigned short h8[8];
        #pragma unroll
        for (int e = 0; e < 8; ++e) {
            int ic = icb + e;
            float s = 0.f;
            for (int c = 0; c < 64; ++c)
                s += W_dc[oc * 64 + c] * W_sp[(c * 64 + ic) * 49 + tap];
            h8[e] = f2bf(s);
        }
        #pragma unroll
        for (int e = 0; e < 8; ++e) WpH[idx * 8 + e] = h8[e];
        return;
    } else if (blk < 111) {
        int idx = (blk - 98) * 256 + tid;
        if (idx < 2048) {
            int lane = idx & 63, ks = (idx >> 6) & 3, nf = (idx >> 8) & 3, hl = idx >> 10;
            int o = nf * 32 + (lane & 31), cb = ks * 16 + (lane >> 5) * 8;
            #pragma unroll
            for (int e = 0; e < 8; ++e) {
                float v = W_in[o * 64 + cb + e] * gn_g[cb + e];
                unsigned short h = f2bf(v);
                WP1[idx * 8 + e] = hl ? f2bf(v - bf2f(h)) : h;
            }
        } else if (idx < 3072) {
            int i2 = idx - 2048;
            int lane = i2 & 63, ks = (i2 >> 6) & 3, nf = (i2 >> 8) & 1, hl = i2 >> 9;
            int j = nf * 32 + (lane & 31), ob = ks * 16 + (lane >> 5) * 8;
            #pragma unroll
            for (int e = 0; e < 8; ++e) {
                float v = W_out[j * 64 + ob + e];
                unsigned short h = f2bf(v);
                WP2[i2 * 8 + e] = hl ? f2bf(v - bf2f(h)) : h;
            }
        } else if (idx < 3200) {
            int o = idx - 3072;
            float s = b_in[o];
            for (int c = 0; c < 64; ++c) s += W_in[o * 64 + c] * gn_b[c];
            OFF1[o] = s;
        }
        return;
    } else if (blk < 119) {
        int idx = (blk - 111) * 256 + tid;
        if (idx >= N_ * C_) return;
        int c = idx & 63, n = idx >> 6;
        float dtv = dt[n];
        float decay = expf(-expf(nu_log[c]) * dtv);
        float phase = expf(theta_log[c]) * dtv;
        lr_t[idx] = decay * cosf(phase);
        li_t[idx] = decay * sinf(phase);
        gm_t[idx] = sqrtf(fmaxf(1.f - decay * decay, 1e-6f));
        return;
    }
    // ---- transpose part
    int blk2 = blk - 119;
    int n = blk2 >> 5, seg = blk2 & 31;
    int p0 = seg * 128;
    int b = n >> 4, l = n & 15;
    for (int i = 0; i < 32; ++i) {
        int idx = i * 256 + tid;
        int ic = idx >> 7, p = idx & 127;
        t[ic][p] = x[(((size_t)(b * 64 + ic) * 16 + l)) * 4096 + p0 + p];
    }
    __syncthreads();
    for (int it = 0; it < 4; ++it) {
        int chunk = it * 256 + tid;
        int p = chunk >> 3, c0 = (chunk & 7) * 8;
        unsigned short h8[8];
        #pragma unroll
        for (int e = 0; e < 8; ++e) h8[e] = f2bf(t[c0 + e][p]);
        size_t off = ((size_t)(n * 4096 + p0 + p)) * 64 + c0;
        *(uint4*)&xhi[off] = *(uint4*)h8;
    }
}

// ---------------- MFMA implicit-GEMM 7x7 conv: B-prefetch before covering MFMA group ----------------
__global__ __launch_bounds__(256, 2) void k_conv(
    const unsigned short* __restrict__ xhi,
    const unsigned short* __restrict__ WpH,
    const float* __restrict__ b_dc, unsigned short* __restrict__ y,
    float* __restrict__ part) {
    __shared__ uint4 halo[3904];
    __shared__ float ps[4][8], pq[4][8];
    int tid = threadIdx.x;
    int lin = blockIdx.x;
    int src = ((lin & 7) << 6) + (lin >> 3);
    int n = src >> 4;
    int tile = src & 15;
    int th = tile >> 2, tw = tile & 3;
    int lane = tid & 63, wid = tid >> 6;
    int dh = (lane >> 4) & 1, dw = lane & 15, kslot = lane >> 5;

    for (int u2 = wid; u2 < 61; u2 += 4) {
        int row = u2 * 8 + (lane >> 3);
        if (row > 483) row = 483;
        int hh = row / 22, ww = row - hh * 22;
        int hs = th * 16 + hh - 3; hs = hs < 0 ? 0 : (hs > 63 ? 63 : hs);
        int wv = (tw * 16 + ww - 3) & 63;
        const uint4* src4 = (const uint4*)(xhi + ((size_t)n * 4096 + hs * 64 + wv) * 64) + (lane & 7);
        uint4 v = *src4;
        *(uint4*)((char*)halo + ((row << 7) + (((lane & 7) ^ (row & 7)) << 4))) = v;
    }
    __syncthreads();

    f32x16 acc[2][2] = {};
    bf16x8 Aa[2][4], Ab[2][4], Ba[2][4], Bb[2][4];

#define LOADA(Areg, khv, kwv) { \
    _Pragma("unroll") for (int m = 0; m < 2; ++m) { \
        int rowb = (wid * 4 + 2 * m + dh + (khv)) * 22 + dw + (kwv); \
        _Pragma("unroll") for (int ks = 0; ks < 4; ++ks) { \
            int byt = (rowb << 7) + (((2 * ks + kslot) ^ (rowb & 7)) << 4); \
            Areg[m][ks] = *(const bf16x8*)((const char*)halo + byt); } } }

#define LOADB(Breg, tap) { \
    const bf16x8* WH = (const bf16x8*)WpH + (size_t)(tap) * 512 + lane; \
    _Pragma("unroll") for (int nf = 0; nf < 2; ++nf) \
        _Pragma("unroll") for (int ks = 0; ks < 4; ++ks) \
            Breg[nf][ks] = WH[(nf * 4 + ks) * 64]; }

#define MFMA_ALL(Areg, Breg) { \
    _Pragma("unroll") for (int ks = 0; ks < 4; ++ks) \
        _Pragma("unroll") for (int m = 0; m < 2; ++m) \
            _Pragma("unroll") for (int nf = 0; nf < 2; ++nf) \
                acc[m][nf] = __builtin_amdgcn_mfma_f32_32x32x16_bf16(Areg[m][ks], Breg[nf][ks], acc[m][nf], 0, 0, 0); }

    int kh = 0, kw = 0;
    LOADA(Aa, 0, 0); LOADB(Ba, 0);
    for (int t = 0; t < 48; t += 2) {
        ++kw; if (kw == 7) { kw = 0; ++kh; }        // tap t+1
        LOADB(Bb, t + 1);                            // issue loads FIRST...
        LOADA(Ab, kh, kw);
        MFMA_ALL(Aa, Ba);                            // ...then 512-cyc MFMA covers them
        ++kw; if (kw == 7) { kw = 0; ++kh; }        // tap t+2
        LOADB(Ba, t + 2);
        LOADA(Aa, kh, kw);
        MFMA_ALL(Ab, Bb);
    }
    MFMA_ALL(Aa, Ba);                                // tap 48
#undef LOADA
#undef LOADB
#undef MFMA_ALL

    // epilogue: store y (bf16) + per-block GN partial sums (fp32)
    int ocl = lane & 31;
    float sg[2], qg[2];
    #pragma unroll
    for (int nf = 0; nf < 2; ++nf) {
        float bv = b_dc[nf * 32 + ocl];
        float ss = 0.f, qq = 0.f;
        #pragma unroll
        for (int m = 0; m < 2; ++m) {
            #pragma unroll
            for (int j = 0; j < 16; ++j) {
                int r = (j & 3) + 8 * (j >> 2) + 4 * (lane >> 5);
                int h = th * 16 + wid * 4 + 2 * m + (r >> 4);
                int w = tw * 16 + (r & 15);
                float v = acc[m][nf][j] + bv;
                y[((size_t)n * 4096 + h * 64 + w) * 64 + nf * 32 + ocl] = f2bf(v);
                ss += v; qq += v * v;
            }
        }
        sg[nf] = ss; qg[nf] = qq;
    }
    #pragma unroll
    for (int off = 1; off < 16; off <<= 1) {
        sg[0] += __shfl_xor(sg[0], off);
        qg[0] += __shfl_xor(qg[0], off);
        sg[1] += __shfl_xor(sg[1], off);
        qg[1] += __shfl_xor(qg[1], off);
    }
    if ((lane & 15) == 0) {
        int cl = lane >> 4;
        int g0 = cl & 1, slot = wid * 2 + (cl >> 1);
        ps[g0][slot] = sg[0];     pq[g0][slot] = qg[0];
        ps[2 + g0][slot] = sg[1]; pq[2 + g0][slot] = qg[1];
    }
    __syncthreads();
    if (tid < 4) {
        float ss = 0.f, qq = 0.f;
        #pragma unroll
        for (int k2 = 0; k2 < 8; ++k2) { ss += ps[tid][k2]; qq += pq[tid][k2]; }
        part[((size_t)(n * 16 + tile)) * 8 + tid * 2]     = ss;
        part[((size_t)(n * 16 + tile)) * 8 + tid * 2 + 1] = qq;
    }
}

// ---------------- MFMA pointwise: residual from bf16 x-plane, u bf16 in-place ----------------
__global__ __launch_bounds__(256, 1) void k_pw(
    const unsigned short* __restrict__ y, const float* __restrict__ part,
    const unsigned short* __restrict__ WP1, const unsigned short* __restrict__ WP2,
    const float* __restrict__ OFF1, const float* __restrict__ b_out,
    unsigned short* __restrict__ xr) {
    __shared__ __align__(16) char lds[4 * 8704];
    int tid = threadIdx.x, lane = tid & 63, wid = tid >> 6;
    int blk = blockIdx.x;
    int n = blk >> 5, sub = blk & 31;
    int ocl = lane & 31, hi5 = lane >> 5;
    int pixw = sub * 128 + wid * 32;
    char* myl = lds + wid * 8704;

    float mu[4], rsd[4];
    #pragma unroll
    for (int g = 0; g < 4; ++g) {
        float sm = 0.f, sq = 0.f;
        #pragma unroll
        for (int ch = 0; ch < 16; ++ch) {
            sm += part[(n * 16 + ch) * 8 + g * 2];
            sq += part[(n * 16 + ch) * 8 + g * 2 + 1];
        }
        float mean = sm * (1.f / 65536.f);
        float var  = sq * (1.f / 65536.f) - mean * mean;
        mu[g] = mean;
        rsd[g] = rsqrtf(var + 1e-5f);
    }

    const bf16x8* W1 = (const bf16x8*)WP1;
    const bf16x8* W2 = (const bf16x8*)WP2;

    int prow = pixw + ocl;

    bf16x8 A1[4];
    #pragma unroll
    for (int ks = 0; ks < 4; ++ks) {
        bf16x8 raw = *(const bf16x8*)&y[(size_t)(n * 4096 + prow) * 64 + ks * 16 + hi5 * 8];
        float m = mu[ks], r = rsd[ks];
        bf16x8 a;
        #pragma unroll
        for (int e = 0; e < 8; ++e)
            a[e] = (short)f2bf((bf2f((unsigned short)raw[e]) - m) * r);
        A1[ks] = a;
    }

    f32x16 acc1[4];
    #pragma unroll
    for (int nf = 0; nf < 4; ++nf) {
        float o0 = OFF1[nf * 32 + ocl];
        #pragma unroll
        for (int j = 0; j < 16; ++j) acc1[nf][j] = o0;
    }
    __builtin_amdgcn_s_setprio(1);
    #pragma unroll
    for (int ks = 0; ks < 4; ++ks)
        #pragma unroll
        for (int nf = 0; nf < 4; ++nf) {
            bf16x8 bh = W1[nf * 256 + ks * 64 + lane];
            bf16x8 bl = W1[1024 + nf * 256 + ks * 64 + lane];
            acc1[nf] = __builtin_amdgcn_mfma_f32_32x32x16_bf16(A1[ks], bh, acc1[nf], 0, 0, 0);
            acc1[nf] = __builtin_amdgcn_mfma_f32_32x32x16_bf16(A1[ks], bl, acc1[nf], 0, 0, 0);
        }
    __builtin_amdgcn_s_setprio(0);

    unsigned short* zp = (unsigned short*)myl;
    #pragma unroll
    for (int nf = 0; nf < 2; ++nf)
        #pragma unroll
        for (int j = 0; j < 16; ++j) {
            int r = (j & 3) + 8 * (j >> 2) + 4 * hi5;
            float x1 = acc1[nf][j], x2 = acc1[nf + 2][j];
            float z = x1 / (1.f + __expf(-x2));
            zp[r * 68 + nf * 32 + ocl] = f2bf(z);
        }
    asm volatile("s_waitcnt lgkmcnt(0)" ::: "memory");
    __builtin_amdgcn_sched_barrier(0);

    bf16x8 A2[4];
    #pragma unroll
    for (int ks = 0; ks < 4; ++ks)
        A2[ks] = *(const bf16x8*)(myl + ocl * 136 + ks * 32 + hi5 * 16);

    f32x16 acc2[2];
    #pragma unroll
    for (int nf = 0; nf < 2; ++nf)
        #pragma unroll
        for (int j = 0; j < 16; ++j) acc2[nf][j] = 0.f;
    __builtin_amdgcn_s_setprio(1);
    #pragma unroll
    for (int ks = 0; ks < 4; ++ks)
        #pragma unroll
        for (int nf = 0; nf < 2; ++nf) {
            bf16x8 bh = W2[nf * 256 + ks * 64 + lane];
            bf16x8 bl = W2[512 + nf * 256 + ks * 64 + lane];
            acc2[nf] = __builtin_amdgcn_mfma_f32_32x32x16_bf16(A2[ks], bh, acc2[nf], 0, 0, 0);
            acc2[nf] = __builtin_amdgcn_mfma_f32_32x32x16_bf16(A2[ks], bl, acc2[nf], 0, 0, 0);
        }
    __builtin_amdgcn_s_setprio(0);
    asm volatile("s_waitcnt lgkmcnt(0)" ::: "memory");
    __builtin_amdgcn_sched_barrier(0);

    float* up = (float*)myl;
    #pragma unroll
    for (int nf = 0; nf < 2; ++nf)
        #pragma unroll
        for (int j = 0; j < 16; ++j) {
            int r = (j & 3) + 8 * (j >> 2) + 4 * hi5;
            up[r * 68 + nf * 32 + ocl] = acc2[nf][j];
        }
    asm volatile("s_waitcnt lgkmcnt(0)" ::: "memory");
    __builtin_amdgcn_sched_barrier(0);

    // residual from bf16 x-plane + b_out, convert to bf16, store u in-place over xr
    {
        const float* rowp = up + ocl * 68 + hi5 * 32;
        float vrow[32];
        #pragma unroll
        for (int c4 = 0; c4 < 8; ++c4) {
            float4 v = *(const float4*)&rowp[c4 * 4];
            vrow[c4 * 4 + 0] = v.x; vrow[c4 * 4 + 1] = v.y;
            vrow[c4 * 4 + 2] = v.z; vrow[c4 * 4 + 3] = v.w;
        }
        int pixg = pixw + ocl;
        unsigned short* xrow = &xr[((size_t)(n * 4096 + pixg)) * 64 + hi5 * 32];
        bf16x8 xv0 = *(const bf16x8*)&xrow[0];
        bf16x8 xv1 = *(const bf16x8*)&xrow[8];
        bf16x8 xv2 = *(const bf16x8*)&xrow[16];
        bf16x8 xv3 = *(const bf16x8*)&xrow[24];
        unsigned short h16[32];
        #pragma unroll
        for (int e = 0; e < 8; ++e) {
            h16[e]      = f2bf(vrow[e]      + b_out[hi5 * 32 + e]      + bf2f((unsigned short)xv0[e]));
            h16[8 + e]  = f2bf(vrow[8 + e]  + b_out[hi5 * 32 + 8 + e]  + bf2f((unsigned short)xv1[e]));
            h16[16 + e] = f2bf(vrow[16 + e] + b_out[hi5 * 32 + 16 + e] + bf2f((unsigned short)xv2[e]));
            h16[24 + e] = f2bf(vrow[24 + e] + b_out[hi5 * 32 + 24 + e] + bf2f((unsigned short)xv3[e]));
        }
        *(uint4*)&xrow[0]  = *(uint4*)&h16[0];
        *(uint4*)&xrow[8]  = *(uint4*)&h16[8];
        *(uint4*)&xrow[16] = *(uint4*)&h16[16];
        *(uint4*)&xrow[24] = *(uint4*)&h16[24];
    }
}

// ---------------- LRU scan: 2048 blocks, 1 c/thread, LDS lambda tables, prefetch ----------------
__global__ __launch_bounds__(256) void k_scan(
    const unsigned short* __restrict__ u16, const float* __restrict__ lr_t,
    const float* __restrict__ li_t, const float* __restrict__ gm_t,
    const float* __restrict__ c_re, const float* __restrict__ c_im,
    const float* __restrict__ d_skip, float* __restrict__ out) {
    __shared__ float us[2][16][17];
    __shared__ float lsr[16][16], lsi[16][16], lsg[16][16];   // [l][c16]
    int tid = threadIdx.x;
    int bid = blockIdx.x;
    int b = bid >> 10, h = (bid >> 4) & 63, wq = (bid >> 2) & 3, ch = bid & 3;
    int c16 = tid & 15, p = tid >> 4;
    int w = wq * 16 + p;
    int cb = ch * 16 + c16;
    {
        int li = (b * 16 + p) * 64 + ch * 16 + c16;
        lsr[p][c16] = lr_t[li];
        lsi[p][c16] = li_t[li];
        lsg[p][c16] = gm_t[li];
    }
    float cr = c_re[cb], ci = c_im[cb], ds = d_skip[cb];
    float hr = 0.f, hi = 0.f;
    int wp = tid & 15, cc = tid >> 4;
    size_t ubase = ((size_t)(b * 16) * 4096 + h * 64 + w) * 64 + cb;
    float uv = bf2f(u16[ubase]);
    __syncthreads();
    for (int l = 0; l < 16; ++l) {
        float uvn = 0.f;
        if (l < 15) uvn = bf2f(u16[ubase + (size_t)(l + 1) * 262144]);
        float lr = lsr[l][c16], li = lsi[l][c16], gm = lsg[l][c16];
        float nr = lr * hr - li * hi + gm * uv;
        float ni = li * hr + lr * hi;
        float yv = cr * nr + ci * ni + ds * uv;
        hr = nr; hi = ni;
        us[l & 1][p][c16] = yv;
        __syncthreads();
        out[((size_t)(b * 64 + ch * 16 + cc) * 16 + l) * 4096 + h * 64 + wq * 16 + wp] = us[l & 1][wp][cc];
        uv = uvn;
    }
}

extern "C" void kernel_launch(void* const* d_in, const int* in_sizes, int n_in,
                              void* d_out, int out_size, void* d_ws, size_t ws_size,
                              hipStream_t stream) {
    const float* x        = (const float*)d_in[0];
    const float* dt       = (const float*)d_in[1];
    const float* W_sp     = (const float*)d_in[2];
    const float* W_dc     = (const float*)d_in[3];
    const float* b_dc     = (const float*)d_in[4];
    const float* gn_g     = (const float*)d_in[5];
    const float* gn_b     = (const float*)d_in[6];
    const float* W_in     = (const float*)d_in[7];
    const float* b_in     = (const float*)d_in[8];
    const float* W_out    = (const float*)d_in[9];
    const float* b_out    = (const float*)d_in[10];
    const float* nu_log   = (const float*)d_in[11];
    const float* theta_log= (const float*)d_in[12];
    const float* c_re     = (const float*)d_in[13];
    const float* c_im     = (const float*)d_in[14];
    const float* d_skip   = (const float*)d_in[15];

    char* ws = (char*)d_ws;
    unsigned short* WpH  = (unsigned short*)(ws + BY_WPH);
    unsigned short* WP1  = (unsigned short*)(ws + BY_WP1);
    unsigned short* WP2  = (unsigned short*)(ws + BY_WP2);
    float* OFF1   = (float*)(ws + BY_OFF1);
    float* lr_t   = (float*)(ws + BY_LR);
    float* li_t   = (float*)(ws + BY_LI);
    float* gm_t   = (float*)(ws + BY_GM);
    float* part   = (float*)(ws + BY_PART);
    unsigned short* xhi = (unsigned short*)(ws + BY_XHI);   // becomes u (bf16) after k_pw
    unsigned short* y16 = (unsigned short*)d_out;           // bf16 y in d_out until k_pw
    float* out    = (float*)d_out;

    hipLaunchKernelGGL(k_pre,     dim3(1143),      dim3(256), 0, stream,
                       W_sp, W_dc, WpH, W_in, b_in, W_out, gn_g, gn_b, WP1, WP2, OFF1,
                       dt, nu_log, theta_log, lr_t, li_t, gm_t, x, xhi);
    hipLaunchKernelGGL(k_conv,    dim3(512),       dim3(256), 0, stream, xhi, WpH, b_dc, y16, part);
    hipLaunchKernelGGL(k_pw,      dim3(1024),      dim3(256), 0, stream, y16, part, WP1, WP2,
                       OFF1, b_out, xhi);
    hipLaunchKernelGGL(k_scan,    dim3(2048),      dim3(256), 0, stream, xhi, lr_t, li_t, gm_t,
                       c_re, c_im, d_skip, out);
}

// Round 18
// 124.328 us; speedup vs baseline: 1.0102x; 1.0102x over previous
//
#include <hip/hip_runtime.h>
#include <hip/hip_bf16.h>

typedef short bf16x8 __attribute__((ext_vector_type(8)));
typedef float f32x16 __attribute__((ext_vector_type(16)));

#define B_ 2
#define C_ 64
#define L_ 16
#define N_ 32
#define HW_ 4096

// ---- ws byte layout ----
#define BY_WPH  0u          // conv packed weights: 25088 frags * 16B = 401408
#define BY_WP1  401408u     // W_in' B-frags hi/lo
#define BY_WP2  434176u     // W_out B-frags hi/lo
#define BY_OFF1 450560u
#define BY_LR   451072u
#define BY_LI   459264u
#define BY_GM   467456u
#define BY_PART 475648u     // conv per-block gn partials
#define BY_XHI  524288u     // x bf16 plane [n][pix][ic]; after k_pw: u bf16 (in-place)

__device__ __forceinline__ unsigned short f2bf(float v) {
    unsigned int u = __float_as_uint(v);
    unsigned int r = u + 0x7FFFu + ((u >> 16) & 1u);
    return (unsigned short)(r >> 16);
}
__device__ __forceinline__ float bf2f(unsigned short s) {
    return __uint_as_float(((unsigned int)s) << 16);
}

// ---------------- merged: setup (blocks 0..118) | x transpose (blocks 119..1142) ----------------
__global__ __launch_bounds__(256) void k_pre(
    const float* __restrict__ W_sp, const float* __restrict__ W_dc,
    unsigned short* __restrict__ WpH,
    const float* __restrict__ W_in, const float* __restrict__ b_in,
    const float* __restrict__ W_out,
    const float* __restrict__ gn_g, const float* __restrict__ gn_b,
    unsigned short* __restrict__ WP1, unsigned short* __restrict__ WP2,
    float* __restrict__ OFF1,
    const float* __restrict__ dt, const float* __restrict__ nu_log,
    const float* __restrict__ theta_log,
    float* __restrict__ lr_t, float* __restrict__ li_t, float* __restrict__ gm_t,
    const float* __restrict__ x, unsigned short* __restrict__ xhi) {
    __shared__ float t[64][129];
    int blk = blockIdx.x, tid = threadIdx.x;
    if (blk < 98) {
        int idx = blk * 256 + tid;
        int lane = idx & 63;
        int ks   = (idx >> 6) & 3;
        int nf   = (idx >> 8) & 1;
        int tap  = idx >> 9;
        int oc   = nf * 32 + (lane & 31);
        int icb  = ks * 16 + (lane >> 5) * 8;
        unsigned short h8[8];
        #pragma unroll
        for (int e = 0; e < 8; ++e) {
            int ic = icb + e;
            float s = 0.f;
            for (int c = 0; c < 64; ++c)
                s += W_dc[oc * 64 + c] * W_sp[(c * 64 + ic) * 49 + tap];
            h8[e] = f2bf(s);
        }
        #pragma unroll
        for (int e = 0; e < 8; ++e) WpH[idx * 8 + e] = h8[e];
        return;
    } else if (blk < 111) {
        int idx = (blk - 98) * 256 + tid;
        if (idx < 2048) {
            int lane = idx & 63, ks = (idx >> 6) & 3, nf = (idx >> 8) & 3, hl = idx >> 10;
            int o = nf * 32 + (lane & 31), cb = ks * 16 + (lane >> 5) * 8;
            #pragma unroll
            for (int e = 0; e < 8; ++e) {
                float v = W_in[o * 64 + cb + e] * gn_g[cb + e];
                unsigned short h = f2bf(v);
                WP1[idx * 8 + e] = hl ? f2bf(v - bf2f(h)) : h;
            }
        } else if (idx < 3072) {
            int i2 = idx - 2048;
            int lane = i2 & 63, ks = (i2 >> 6) & 3, nf = (i2 >> 8) & 1, hl = i2 >> 9;
            int j = nf * 32 + (lane & 31), ob = ks * 16 + (lane >> 5) * 8;
            #pragma unroll
            for (int e = 0; e < 8; ++e) {
                float v = W_out[j * 64 + ob + e];
                unsigned short h = f2bf(v);
                WP2[i2 * 8 + e] = hl ? f2bf(v - bf2f(h)) : h;
            }
        } else if (idx < 3200) {
            int o = idx - 3072;
            float s = b_in[o];
            for (int c = 0; c < 64; ++c) s += W_in[o * 64 + c] * gn_b[c];
            OFF1[o] = s;
        }
        return;
    } else if (blk < 119) {
        int idx = (blk - 111) * 256 + tid;
        if (idx >= N_ * C_) return;
        int c = idx & 63, n = idx >> 6;
        float dtv = dt[n];
        float decay = expf(-expf(nu_log[c]) * dtv);
        float phase = expf(theta_log[c]) * dtv;
        lr_t[idx] = decay * cosf(phase);
        li_t[idx] = decay * sinf(phase);
        gm_t[idx] = sqrtf(fmaxf(1.f - decay * decay, 1e-6f));
        return;
    }
    // ---- transpose part
    int blk2 = blk - 119;
    int n = blk2 >> 5, seg = blk2 & 31;
    int p0 = seg * 128;
    int b = n >> 4, l = n & 15;
    for (int i = 0; i < 32; ++i) {
        int idx = i * 256 + tid;
        int ic = idx >> 7, p = idx & 127;
        t[ic][p] = x[(((size_t)(b * 64 + ic) * 16 + l)) * 4096 + p0 + p];
    }
    __syncthreads();
    for (int it = 0; it < 4; ++it) {
        int chunk = it * 256 + tid;
        int p = chunk >> 3, c0 = (chunk & 7) * 8;
        unsigned short h8[8];
        #pragma unroll
        for (int e = 0; e < 8; ++e) h8[e] = f2bf(t[c0 + e][p]);
        size_t off = ((size_t)(n * 4096 + p0 + p)) * 64 + c0;
        *(uint4*)&xhi[off] = *(uint4*)h8;
    }
}

// ---------------- MFMA implicit-GEMM 7x7 conv (r13 structure + XCD-chunked swizzle) ----------------
__global__ __launch_bounds__(256, 2) void k_conv(
    const unsigned short* __restrict__ xhi,
    const unsigned short* __restrict__ WpH,
    const float* __restrict__ b_dc, unsigned short* __restrict__ y,
    float* __restrict__ part) {
    __shared__ uint4 halo[3904];
    __shared__ float ps[4][8], pq[4][8];
    int tid = threadIdx.x;
    int lin = blockIdx.x;
    int src = ((lin & 7) << 6) + (lin >> 3);
    int n = src >> 4;
    int tile = src & 15;
    int th = tile >> 2, tw = tile & 3;
    int lane = tid & 63, wid = tid >> 6;
    int dh = (lane >> 4) & 1, dw = lane & 15, kslot = lane >> 5;

    for (int u2 = wid; u2 < 61; u2 += 4) {
        int row = u2 * 8 + (lane >> 3);
        if (row > 483) row = 483;
        int hh = row / 22, ww = row - hh * 22;
        int hs = th * 16 + hh - 3; hs = hs < 0 ? 0 : (hs > 63 ? 63 : hs);
        int wv = (tw * 16 + ww - 3) & 63;
        const uint4* src4 = (const uint4*)(xhi + ((size_t)n * 4096 + hs * 64 + wv) * 64) + (lane & 7);
        uint4 v = *src4;
        *(uint4*)((char*)halo + ((row << 7) + (((lane & 7) ^ (row & 7)) << 4))) = v;
    }
    __syncthreads();

    f32x16 acc[2][2] = {};
    bf16x8 Aa[2][4], Ab[2][4], Ba[2][4], Bb[2][4];

#define LOADA(Areg, khv, kwv) { \
    _Pragma("unroll") for (int m = 0; m < 2; ++m) { \
        int rowb = (wid * 4 + 2 * m + dh + (khv)) * 22 + dw + (kwv); \
        _Pragma("unroll") for (int ks = 0; ks < 4; ++ks) { \
            int byt = (rowb << 7) + (((2 * ks + kslot) ^ (rowb & 7)) << 4); \
            Areg[m][ks] = *(const bf16x8*)((const char*)halo + byt); } } }

#define LOADB(Breg, tap) { \
    const bf16x8* WH = (const bf16x8*)WpH + (size_t)(tap) * 512 + lane; \
    _Pragma("unroll") for (int nf = 0; nf < 2; ++nf) \
        _Pragma("unroll") for (int ks = 0; ks < 4; ++ks) \
            Breg[nf][ks] = WH[(nf * 4 + ks) * 64]; }

#define MFMA_ALL(Areg, Breg) { \
    _Pragma("unroll") for (int ks = 0; ks < 4; ++ks) \
        _Pragma("unroll") for (int m = 0; m < 2; ++m) \
            _Pragma("unroll") for (int nf = 0; nf < 2; ++nf) \
                acc[m][nf] = __builtin_amdgcn_mfma_f32_32x32x16_bf16(Areg[m][ks], Breg[nf][ks], acc[m][nf], 0, 0, 0); }

    int kh = 0, kw = 0;
    LOADA(Aa, 0, 0); LOADB(Ba, 0);
    for (int t = 0; t < 48; t += 2) {
        ++kw; if (kw == 7) { kw = 0; ++kh; }        // tap t+1
        LOADA(Ab, kh, kw);
        MFMA_ALL(Aa, Ba);                            // tap t
        LOADB(Bb, t + 1);
        ++kw; if (kw == 7) { kw = 0; ++kh; }        // tap t+2
        LOADA(Aa, kh, kw);
        MFMA_ALL(Ab, Bb);                            // tap t+1
        LOADB(Ba, t + 2);
    }
    MFMA_ALL(Aa, Ba);                                // tap 48
#undef LOADA
#undef LOADB
#undef MFMA_ALL

    // epilogue: store y (bf16) + per-block GN partial sums (fp32)
    int ocl = lane & 31;
    float sg[2], qg[2];
    #pragma unroll
    for (int nf = 0; nf < 2; ++nf) {
        float bv = b_dc[nf * 32 + ocl];
        float ss = 0.f, qq = 0.f;
        #pragma unroll
        for (int m = 0; m < 2; ++m) {
            #pragma unroll
            for (int j = 0; j < 16; ++j) {
                int r = (j & 3) + 8 * (j >> 2) + 4 * (lane >> 5);
                int h = th * 16 + wid * 4 + 2 * m + (r >> 4);
                int w = tw * 16 + (r & 15);
                float v = acc[m][nf][j] + bv;
                y[((size_t)n * 4096 + h * 64 + w) * 64 + nf * 32 + ocl] = f2bf(v);
                ss += v; qq += v * v;
            }
        }
        sg[nf] = ss; qg[nf] = qq;
    }
    #pragma unroll
    for (int off = 1; off < 16; off <<= 1) {
        sg[0] += __shfl_xor(sg[0], off);
        qg[0] += __shfl_xor(qg[0], off);
        sg[1] += __shfl_xor(sg[1], off);
        qg[1] += __shfl_xor(qg[1], off);
    }
    if ((lane & 15) == 0) {
        int cl = lane >> 4;
        int g0 = cl & 1, slot = wid * 2 + (cl >> 1);
        ps[g0][slot] = sg[0];     pq[g0][slot] = qg[0];
        ps[2 + g0][slot] = sg[1]; pq[2 + g0][slot] = qg[1];
    }
    __syncthreads();
    if (tid < 4) {
        float ss = 0.f, qq = 0.f;
        #pragma unroll
        for (int k2 = 0; k2 < 8; ++k2) { ss += ps[tid][k2]; qq += pq[tid][k2]; }
        part[((size_t)(n * 16 + tile)) * 8 + tid * 2]     = ss;
        part[((size_t)(n * 16 + tile)) * 8 + tid * 2 + 1] = qq;
    }
}

// ---------------- MFMA pointwise: residual from bf16 x-plane, u bf16 in-place ----------------
__global__ __launch_bounds__(256, 1) void k_pw(
    const unsigned short* __restrict__ y, const float* __restrict__ part,
    const unsigned short* __restrict__ WP1, const unsigned short* __restrict__ WP2,
    const float* __restrict__ OFF1, const float* __restrict__ b_out,
    unsigned short* __restrict__ xr) {
    __shared__ __align__(16) char lds[4 * 8704];
    int tid = threadIdx.x, lane = tid & 63, wid = tid >> 6;
    int blk = blockIdx.x;
    int n = blk >> 5, sub = blk & 31;
    int ocl = lane & 31, hi5 = lane >> 5;
    int pixw = sub * 128 + wid * 32;
    char* myl = lds + wid * 8704;

    float mu[4], rsd[4];
    #pragma unroll
    for (int g = 0; g < 4; ++g) {
        float sm = 0.f, sq = 0.f;
        #pragma unroll
        for (int ch = 0; ch < 16; ++ch) {
            sm += part[(n * 16 + ch) * 8 + g * 2];
            sq += part[(n * 16 + ch) * 8 + g * 2 + 1];
        }
        float mean = sm * (1.f / 65536.f);
        float var  = sq * (1.f / 65536.f) - mean * mean;
        mu[g] = mean;
        rsd[g] = rsqrtf(var + 1e-5f);
    }

    const bf16x8* W1 = (const bf16x8*)WP1;
    const bf16x8* W2 = (const bf16x8*)WP2;

    int prow = pixw + ocl;

    bf16x8 A1[4];
    #pragma unroll
    for (int ks = 0; ks < 4; ++ks) {
        bf16x8 raw = *(const bf16x8*)&y[(size_t)(n * 4096 + prow) * 64 + ks * 16 + hi5 * 8];
        float m = mu[ks], r = rsd[ks];
        bf16x8 a;
        #pragma unroll
        for (int e = 0; e < 8; ++e)
            a[e] = (short)f2bf((bf2f((unsigned short)raw[e]) - m) * r);
        A1[ks] = a;
    }

    f32x16 acc1[4];
    #pragma unroll
    for (int nf = 0; nf < 4; ++nf) {
        float o0 = OFF1[nf * 32 + ocl];
        #pragma unroll
        for (int j = 0; j < 16; ++j) acc1[nf][j] = o0;
    }
    __builtin_amdgcn_s_setprio(1);
    #pragma unroll
    for (int ks = 0; ks < 4; ++ks)
        #pragma unroll
        for (int nf = 0; nf < 4; ++nf) {
            bf16x8 bh = W1[nf * 256 + ks * 64 + lane];
            bf16x8 bl = W1[1024 + nf * 256 + ks * 64 + lane];
            acc1[nf] = __builtin_amdgcn_mfma_f32_32x32x16_bf16(A1[ks], bh, acc1[nf], 0, 0, 0);
            acc1[nf] = __builtin_amdgcn_mfma_f32_32x32x16_bf16(A1[ks], bl, acc1[nf], 0, 0, 0);
        }
    __builtin_amdgcn_s_setprio(0);

    unsigned short* zp = (unsigned short*)myl;
    #pragma unroll
    for (int nf = 0; nf < 2; ++nf)
        #pragma unroll
        for (int j = 0; j < 16; ++j) {
            int r = (j & 3) + 8 * (j >> 2) + 4 * hi5;
            float x1 = acc1[nf][j], x2 = acc1[nf + 2][j];
            float z = x1 / (1.f + __expf(-x2));
            zp[r * 68 + nf * 32 + ocl] = f2bf(z);
        }
    asm volatile("s_waitcnt lgkmcnt(0)" ::: "memory");
    __builtin_amdgcn_sched_barrier(0);

    bf16x8 A2[4];
    #pragma unroll
    for (int ks = 0; ks < 4; ++ks)
        A2[ks] = *(const bf16x8*)(myl + ocl * 136 + ks * 32 + hi5 * 16);

    f32x16 acc2[2];
    #pragma unroll
    for (int nf = 0; nf < 2; ++nf)
        #pragma unroll
        for (int j = 0; j < 16; ++j) acc2[nf][j] = 0.f;
    __builtin_amdgcn_s_setprio(1);
    #pragma unroll
    for (int ks = 0; ks < 4; ++ks)
        #pragma unroll
        for (int nf = 0; nf < 2; ++nf) {
            bf16x8 bh = W2[nf * 256 + ks * 64 + lane];
            bf16x8 bl = W2[512 + nf * 256 + ks * 64 + lane];
            acc2[nf] = __builtin_amdgcn_mfma_f32_32x32x16_bf16(A2[ks], bh, acc2[nf], 0, 0, 0);
            acc2[nf] = __builtin_amdgcn_mfma_f32_32x32x16_bf16(A2[ks], bl, acc2[nf], 0, 0, 0);
        }
    __builtin_amdgcn_s_setprio(0);
    asm volatile("s_waitcnt lgkmcnt(0)" ::: "memory");
    __builtin_amdgcn_sched_barrier(0);

    float* up = (float*)myl;
    #pragma unroll
    for (int nf = 0; nf < 2; ++nf)
        #pragma unroll
        for (int j = 0; j < 16; ++j) {
            int r = (j & 3) + 8 * (j >> 2) + 4 * hi5;
            up[r * 68 + nf * 32 + ocl] = acc2[nf][j];
        }
    asm volatile("s_waitcnt lgkmcnt(0)" ::: "memory");
    __builtin_amdgcn_sched_barrier(0);

    // residual from bf16 x-plane + b_out, convert to bf16, store u in-place over xr
    {
        const float* rowp = up + ocl * 68 + hi5 * 32;
        float vrow[32];
        #pragma unroll
        for (int c4 = 0; c4 < 8; ++c4) {
            float4 v = *(const float4*)&rowp[c4 * 4];
            vrow[c4 * 4 + 0] = v.x; vrow[c4 * 4 + 1] = v.y;
            vrow[c4 * 4 + 2] = v.z; vrow[c4 * 4 + 3] = v.w;
        }
        int pixg = pixw + ocl;
        unsigned short* xrow = &xr[((size_t)(n * 4096 + pixg)) * 64 + hi5 * 32];
        bf16x8 xv0 = *(const bf16x8*)&xrow[0];
        bf16x8 xv1 = *(const bf16x8*)&xrow[8];
        bf16x8 xv2 = *(const bf16x8*)&xrow[16];
        bf16x8 xv3 = *(const bf16x8*)&xrow[24];
        unsigned short h16[32];
        #pragma unroll
        for (int e = 0; e < 8; ++e) {
            h16[e]      = f2bf(vrow[e]      + b_out[hi5 * 32 + e]      + bf2f((unsigned short)xv0[e]));
            h16[8 + e]  = f2bf(vrow[8 + e]  + b_out[hi5 * 32 + 8 + e]  + bf2f((unsigned short)xv1[e]));
            h16[16 + e] = f2bf(vrow[16 + e] + b_out[hi5 * 32 + 16 + e] + bf2f((unsigned short)xv2[e]));
            h16[24 + e] = f2bf(vrow[24 + e] + b_out[hi5 * 32 + 24 + e] + bf2f((unsigned short)xv3[e]));
        }
        *(uint4*)&xrow[0]  = *(uint4*)&h16[0];
        *(uint4*)&xrow[8]  = *(uint4*)&h16[8];
        *(uint4*)&xrow[16] = *(uint4*)&h16[16];
        *(uint4*)&xrow[24] = *(uint4*)&h16[24];
    }
}

// ---------------- LRU scan: 2048 blocks, 1 c/thread, LDS lambda tables, prefetch ----------------
__global__ __launch_bounds__(256) void k_scan(
    const unsigned short* __restrict__ u16, const float* __restrict__ lr_t,
    const float* __restrict__ li_t, const float* __restrict__ gm_t,
    const float* __restrict__ c_re, const float* __restrict__ c_im,
    const float* __restrict__ d_skip, float* __restrict__ out) {
    __shared__ float us[2][16][17];
    __shared__ float lsr[16][16], lsi[16][16], lsg[16][16];   // [l][c16]
    int tid = threadIdx.x;
    int bid = blockIdx.x;
    int b = bid >> 10, h = (bid >> 4) & 63, wq = (bid >> 2) & 3, ch = bid & 3;
    int c16 = tid & 15, p = tid >> 4;
    int w = wq * 16 + p;
    int cb = ch * 16 + c16;
    {
        int li = (b * 16 + p) * 64 + ch * 16 + c16;
        lsr[p][c16] = lr_t[li];
        lsi[p][c16] = li_t[li];
        lsg[p][c16] = gm_t[li];
    }
    float cr = c_re[cb], ci = c_im[cb], ds = d_skip[cb];
    float hr = 0.f, hi = 0.f;
    int wp = tid & 15, cc = tid >> 4;
    size_t ubase = ((size_t)(b * 16) * 4096 + h * 64 + w) * 64 + cb;
    float uv = bf2f(u16[ubase]);
    __syncthreads();
    for (int l = 0; l < 16; ++l) {
        float uvn = 0.f;
        if (l < 15) uvn = bf2f(u16[ubase + (size_t)(l + 1) * 262144]);
        float lr = lsr[l][c16], li = lsi[l][c16], gm = lsg[l][c16];
        float nr = lr * hr - li * hi + gm * uv;
        float ni = li * hr + lr * hi;
        float yv = cr * nr + ci * ni + ds * uv;
        hr = nr; hi = ni;
        us[l & 1][p][c16] = yv;
        __syncthreads();
        out[((size_t)(b * 64 + ch * 16 + cc) * 16 + l) * 4096 + h * 64 + wq * 16 + wp] = us[l & 1][wp][cc];
        uv = uvn;
    }
}

extern "C" void kernel_launch(void* const* d_in, const int* in_sizes, int n_in,
                              void* d_out, int out_size, void* d_ws, size_t ws_size,
                              hipStream_t stream) {
    const float* x        = (const float*)d_in[0];
    const float* dt       = (const float*)d_in[1];
    const float* W_sp     = (const float*)d_in[2];
    const float* W_dc     = (const float*)d_in[3];
    const float* b_dc     = (const float*)d_in[4];
    const float* gn_g     = (const float*)d_in[5];
    const float* gn_b     = (const float*)d_in[6];
    const float* W_in     = (const float*)d_in[7];
    const float* b_in     = (const float*)d_in[8];
    const float* W_out    = (const float*)d_in[9];
    const float* b_out    = (const float*)d_in[10];
    const float* nu_log   = (const float*)d_in[11];
    const float* theta_log= (const float*)d_in[12];
    const float* c_re     = (const float*)d_in[13];
    const float* c_im     = (const float*)d_in[14];
    const float* d_skip   = (const float*)d_in[15];

    char* ws = (char*)d_ws;
    unsigned short* WpH  = (unsigned short*)(ws + BY_WPH);
    unsigned short* WP1  = (unsigned short*)(ws + BY_WP1);
    unsigned short* WP2  = (unsigned short*)(ws + BY_WP2);
    float* OFF1   = (float*)(ws + BY_OFF1);
    float* lr_t   = (float*)(ws + BY_LR);
    float* li_t   = (float*)(ws + BY_LI);
    float* gm_t   = (float*)(ws + BY_GM);
    float* part   = (float*)(ws + BY_PART);
    unsigned short* xhi = (unsigned short*)(ws + BY_XHI);   // becomes u (bf16) after k_pw
    unsigned short* y16 = (unsigned short*)d_out;           // bf16 y in d_out until k_pw
    float* out    = (float*)d_out;

    hipLaunchKernelGGL(k_pre,     dim3(1143),      dim3(256), 0, stream,
                       W_sp, W_dc, WpH, W_in, b_in, W_out, gn_g, gn_b, WP1, WP2, OFF1,
                       dt, nu_log, theta_log, lr_t, li_t, gm_t, x, xhi);
    hipLaunchKernelGGL(k_conv,    dim3(512),       dim3(256), 0, stream, xhi, WpH, b_dc, y16, part);
    hipLaunchKernelGGL(k_pw,      dim3(1024),      dim3(256), 0, stream, y16, part, WP1, WP2,
                       OFF1, b_out, xhi);
    hipLaunchKernelGGL(k_scan,    dim3(2048),      dim3(256), 0, stream, xhi, lr_t, li_t, gm_t,
                       c_re, c_im, d_skip, out);
}